// Round 4
// baseline (102.623 us; speedup 1.0000x reference)
//
#include <hip/hip_runtime.h>

#define BB 4
#define T_IN 12
#define T_OUT 24
#define NNODE 20000
#define CC 16
#define KP1 9
#define NH 8
#define JJ 12                 // T_OUT - T_IN
#define NODES_PER_BLK 64      // 64 nodes x 4 float4-lanes = 256 threads
#define CHUNKS 313            // ceil(20000/64)
#define PAIRS 157             // ceil(CHUNKS/2): chunk = pairIdx*2 + parity
#define NXCD 8

typedef __attribute__((ext_vector_type(4))) float f4;

__device__ __forceinline__ f4 swish4(f4 s) {
    f4 e;
    e.x = __expf(-0.8f * s.x); e.y = __expf(-0.8f * s.y);
    e.z = __expf(-0.8f * s.z); e.w = __expf(-0.8f * s.w);
    return s / (1.f + e);
}
__device__ __forceinline__ f4 selu4(f4 s) {
    f4 r;
    r.x = (s.x > 0.f) ? 1.0507009873554805f * s.x : 1.7580993408473766f * (__expf(s.x) - 1.f);
    r.y = (s.y > 0.f) ? 1.0507009873554805f * s.y : 1.7580993408473766f * (__expf(s.y) - 1.f);
    r.z = (s.z > 0.f) ? 1.0507009873554805f * s.z : 1.7580993408473766f * (__expf(s.z) - 1.f);
    r.w = (s.w > 0.f) ? 1.0507009873554805f * s.w : 1.7580993408473766f * (__expf(s.w) - 1.f);
    return r;
}
__device__ __forceinline__ void nt_store4(f4 v, f4* p) {
    __builtin_nontemporal_store(v, p);
}

// Fully fused: per 64-node chunk, stream t=0..11: gather 9 neighbors ->
// aggregate -> swish -> EMA (register state) -> accumulate collapsed 12x12
// matmul -> x-copy store; epilogue: selu + y store. No staging round-trip.
// blockIdx mapping pins each b to an XCD pair (b = (blockIdx&7)>>1).
__global__ __launch_bounds__(256) void gal_fused(
    const f4* __restrict__ x,        // (B,12,N,16) as f4
    const int* __restrict__ nn,      // (N,9)
    const float* __restrict__ agg_w, // (9,)
    const float* __restrict__ agg_b, // (1,)
    const float* __restrict__ mh_w,  // (8,)
    const float* __restrict__ mh_b,  // (8,)
    const float* __restrict__ shrink_w,  // (12,96)
    const float* __restrict__ shrink_b,  // (12,)
    f4* __restrict__ out)            // (B,24,N,16) as f4
{
    const int xcd = blockIdx.x & (NXCD - 1);
    const int pairIdx = blockIdx.x >> 3;
    const int b = xcd >> 1;
    const int chunk = pairIdx * 2 + (xcd & 1);
    if (chunk >= CHUNKS) return;               // uniform: before any barrier
    const int n_base = chunk * NODES_PER_BLK;

    __shared__ int   sNN[NODES_PER_BLK * KP1];  // 576 ints
    __shared__ float sWc[JJ][T_IN];
    __shared__ float sBc[JJ];

    const int tid = threadIdx.x;

    // cooperative coalesced nn fill
    for (int i = tid; i < NODES_PER_BLK * KP1; i += 256) {
        int gi = n_base * KP1 + i;
        sNN[i] = (gi < NNODE * KP1) ? nn[gi] : NNODE;
    }
    // collapsed weights: Wc[j][t] = sum_h mh_w[h]*W[j,t*8+h]
    if (tid < JJ * T_IN) {
        int j = tid / T_IN, t = tid - j * T_IN;
        float s = 0.f;
#pragma unroll
        for (int h = 0; h < NH; ++h)
            s += mh_w[h] * shrink_w[j * (T_IN * NH) + t * NH + h];
        sWc[j][t] = s;
    }
    if (tid < JJ) {
        float s = shrink_b[tid];
#pragma unroll
        for (int q = 0; q < T_IN * NH; ++q)
            s += mh_b[q & (NH - 1)] * shrink_w[tid * (T_IN * NH) + q];
        sBc[tid] = s;
    }
    __syncthreads();

    const int r = tid >> 2;        // local node 0..63
    const int q = tid & 3;         // f4 lane (channels 4q..4q+3)
    const int n = n_base + r;
    if (n >= NNODE) return;        // no barriers below

    int idx[KP1];
    float w[KP1];
#pragma unroll
    for (int k = 0; k < KP1; ++k) {
        idx[k] = sNN[r * KP1 + k];
        w[k] = agg_w[k];
        if (idx[k] >= NNODE) { idx[k] = 0; w[k] = 0.f; }  // padded zero-node
    }
    const float bias = agg_b[0];

    const f4* xb = x + (size_t)b * (T_IN * NNODE * 4) + q;
    const size_t out_b = (size_t)b * (T_OUT * NNODE * 4);
    const size_t row = (size_t)n * 4 + q;

    f4 acc[JJ];
#pragma unroll
    for (int j = 0; j < JJ; ++j) acc[j] = sBc[j];   // broadcast

    f4 prev;
#pragma unroll
    for (int t = 0; t < T_IN; ++t) {
        const f4* xt = xb + (size_t)t * (NNODE * 4);
        f4 s = bias;
#pragma unroll
        for (int k = 0; k < KP1; ++k)
            s += w[k] * xt[(size_t)idx[k] * 4];
        s = swish4(s);
        f4 ae = (t == 0) ? s : (0.8f * s + 0.2f * prev);
        prev = s;
#pragma unroll
        for (int j = 0; j < JJ; ++j) acc[j] += sWc[j][t] * ae;

        // x-copy (slice is cache-hot from the gathers)
        f4 xv = xt[(size_t)n * 4];
        nt_store4(xv, &out[out_b + (size_t)t * (NNODE * 4) + row]);
    }

#pragma unroll
    for (int j = 0; j < JJ; ++j)
        nt_store4(selu4(acc[j]), &out[out_b + (size_t)(T_IN + j) * (NNODE * 4) + row]);
}

extern "C" void kernel_launch(void* const* d_in, const int* in_sizes, int n_in,
                              void* d_out, int out_size, void* d_ws, size_t ws_size,
                              hipStream_t stream) {
    const float* x        = (const float*)d_in[0];
    const int*   nn       = (const int*)d_in[1];
    const float* agg_w    = (const float*)d_in[2];
    const float* agg_b    = (const float*)d_in[3];
    const float* mh_w     = (const float*)d_in[4];
    const float* mh_b     = (const float*)d_in[5];
    const float* shrink_w = (const float*)d_in[6];
    const float* shrink_b = (const float*)d_in[7];

    gal_fused<<<PAIRS * NXCD, 256, 0, stream>>>(
        (const f4*)x, nn, agg_w, agg_b, mh_w, mh_b, shrink_w, shrink_b,
        (f4*)d_out);
}

// Round 6
// 69.968 us; speedup vs baseline: 1.4667x; 1.4667x over previous
//
#include <hip/hip_runtime.h>

#define BB 4
#define T_IN 12
#define T_OUT 24
#define NNODE 20000
#define CC 16
#define KP1 9
#define NH 8
#define JJ 12                    // T_OUT - T_IN
#define NODES_PER_BLK 64         // 64 nodes x 4 float4-lanes = 256 threads
#define CHUNKS_PER_SLICE 313     // ceil(20000/64)
#define NXCD 8
#define NSLICE (BB * T_IN)       // 48 (b,t) slices
#define SLICES_PER_XCD (NSLICE / NXCD)      // 6
#define PAIRS_PER_XCD (SLICES_PER_XCD / 2)  // 3
#define WS_BF16_BYTES ((size_t)BB * T_IN * NNODE * CC * 2)  // 30.72 MB

typedef __attribute__((ext_vector_type(4))) float f4;
typedef __attribute__((ext_vector_type(4))) unsigned short us4;

__device__ __forceinline__ float swish1(float s) {
    return s / (1.f + __expf(-0.8f * s));
}
__device__ __forceinline__ void nt_store4(const float4& v, float4* p) {
    __builtin_nontemporal_store(*(const f4*)&v, (f4*)p);
}
__device__ __forceinline__ ushort bf16_rne(float f) {
    unsigned u = __float_as_uint(f);
    return (ushort)((u + 0x7FFFu + ((u >> 16) & 1u)) >> 16);
}
__device__ __forceinline__ us4 pack_bf16x4(const float4& v) {
    us4 r;
    r.x = bf16_rne(v.x); r.y = bf16_rne(v.y);
    r.z = bf16_rne(v.z); r.w = bf16_rne(v.w);
    return r;
}
__device__ __forceinline__ float4 unpack_bf16x4(us4 v) {
    float4 r;
    r.x = __uint_as_float((unsigned)v.x << 16);
    r.y = __uint_as_float((unsigned)v.y << 16);
    r.z = __uint_as_float((unsigned)v.z << 16);
    r.w = __uint_as_float((unsigned)v.w << 16);
    return r;
}

// Phase A: two (b,t) slices per block (same b, adjacent t). XCD-pinned slices
// keep the 2.56 MB gather working set L2-resident; nn staged via LDS; stores
// nontemporal. Stage `a` as bf16 into ws (BF16=1) or f32 into out (fallback).
template <int BF16>
__global__ __launch_bounds__(256) void gather_swish(
    const float4* __restrict__ x,    // (B,12,N,16) as float4
    const int* __restrict__ nn,      // (N,9)
    const float* __restrict__ agg_w, // (9,)
    const float* __restrict__ agg_b, // (1,)
    float4* __restrict__ out,        // (B,24,N,16) as float4
    us4* __restrict__ ws)            // (B,12,N,16) bf16 as us4
{
    __shared__ int sNN[NODES_PER_BLK * KP1];   // 576 ints

    const int xcd = blockIdx.x & (NXCD - 1);
    const int j = blockIdx.x >> 3;
    const int pair = j / CHUNKS_PER_SLICE;           // 0..2
    const int chunk = j - pair * CHUNKS_PER_SLICE;
    const int slice0 = xcd * SLICES_PER_XCD + pair * 2;  // = b*12 + t0
    const int b = slice0 / T_IN;
    const int t0 = slice0 - b * T_IN;

    const int tid = threadIdx.x;
    const int n_base = chunk * NODES_PER_BLK;

    for (int i = tid; i < NODES_PER_BLK * KP1; i += 256) {
        int gi = n_base * KP1 + i;
        sNN[i] = (gi < NNODE * KP1) ? nn[gi] : NNODE;
    }
    __syncthreads();

    const int r = tid >> 2;            // local node 0..63
    const int q = tid & 3;             // float4 lane (channels 4q..4q+3)
    const int n = n_base + r;
    if (n >= NNODE) return;

    int idx[KP1];
    float w[KP1];
#pragma unroll
    for (int k = 0; k < KP1; ++k) {
        idx[k] = sNN[r * KP1 + k];
        w[k] = agg_w[k];
        if (idx[k] >= NNODE) { idx[k] = 0; w[k] = 0.f; }  // padded zero-node
    }

    const float bias = agg_b[0];
    const float4* xs0 = x + (size_t)slice0 * (NNODE * 4) + q;
    const float4* xs1 = xs0 + (NNODE * 4);

    float4 s0, s1;
    s0.x = s0.y = s0.z = s0.w = bias;
    s1.x = s1.y = s1.z = s1.w = bias;
#pragma unroll
    for (int k = 0; k < KP1; ++k) {
        float4 v0 = xs0[(size_t)idx[k] * 4];
        float4 v1 = xs1[(size_t)idx[k] * 4];
        float wk = w[k];
        s0.x += wk * v0.x; s0.y += wk * v0.y; s0.z += wk * v0.z; s0.w += wk * v0.w;
        s1.x += wk * v1.x; s1.y += wk * v1.y; s1.z += wk * v1.z; s1.w += wk * v1.w;
    }
    s0.x = swish1(s0.x); s0.y = swish1(s0.y); s0.z = swish1(s0.z); s0.w = swish1(s0.w);
    s1.x = swish1(s1.x); s1.y = swish1(s1.y); s1.z = swish1(s1.z); s1.w = swish1(s1.w);

    const size_t out_b = (size_t)b * (T_OUT * NNODE * 4);
    const size_t row = (size_t)n * 4 + q;
    // copy x -> out[:, t0/t0+1] (slice is L2-hot from gathers)
    float4 xv0 = xs0[(size_t)n * 4];
    float4 xv1 = xs1[(size_t)n * 4];
    nt_store4(xv0, &out[out_b + (size_t)t0 * (NNODE * 4) + row]);
    nt_store4(xv1, &out[out_b + (size_t)(t0 + 1) * (NNODE * 4) + row]);
    // stage a
    if (BF16) {
        const size_t srow = (size_t)slice0 * (NNODE * 4) + row;
        __builtin_nontemporal_store(pack_bf16x4(s0), &ws[srow]);
        __builtin_nontemporal_store(pack_bf16x4(s1), &ws[srow + (NNODE * 4)]);
    } else {
        nt_store4(s0, &out[out_b + (size_t)(T_IN + t0) * (NNODE * 4) + row]);
        nt_store4(s1, &out[out_b + (size_t)(T_IN + t0 + 1) * (NNODE * 4) + row]);
    }
}

// Phase B: EMA over t, collapsed 12x12 matmul, selu; reads staged a (bf16 ws
// or f32 in-place), writes y to out[:, 12:].
template <int BF16>
__global__ __launch_bounds__(256) void ema_shrink(
    const float* __restrict__ mh_w,      // (8,)
    const float* __restrict__ mh_b,      // (8,)
    const float* __restrict__ shrink_w,  // (12,96)
    const float* __restrict__ shrink_b,  // (12,)
    float4* __restrict__ out,            // (B,24,N,16) as float4
    const us4* __restrict__ ws)          // (B,12,N,16) bf16 as us4
{
    __shared__ float sWc[JJ][T_IN];
    __shared__ float sBc[JJ];
    const int tid = threadIdx.x;

    if (tid < JJ * T_IN) {
        int jo = tid / T_IN, t = tid - jo * T_IN;
        float s = 0.f;
#pragma unroll
        for (int h = 0; h < NH; ++h)
            s += mh_w[h] * shrink_w[jo * (T_IN * NH) + t * NH + h];
        sWc[jo][t] = s;
    }
    if (tid < JJ) {
        float s = shrink_b[tid];
#pragma unroll
        for (int qq = 0; qq < T_IN * NH; ++qq)
            s += mh_b[qq & (NH - 1)] * shrink_w[tid * (T_IN * NH) + qq];
        sBc[tid] = s;
    }
    __syncthreads();

    const int g = blockIdx.x * 256 + tid;      // (b, n*4+q) flat, coalesced
    const int b = g / (NNODE * 4);
    const int rem = g - b * (NNODE * 4);
    const size_t base = ((size_t)b * T_OUT + T_IN) * (NNODE * 4) + rem;
    const size_t sbase = (size_t)b * (T_IN * NNODE * 4) + rem;

    float4 a[T_IN];
#pragma unroll
    for (int t = 0; t < T_IN; ++t) {
        if (BF16) {
            us4 v = __builtin_nontemporal_load(&ws[sbase + (size_t)t * (NNODE * 4)]);
            a[t] = unpack_bf16x4(v);
        } else {
            f4 v = __builtin_nontemporal_load((const f4*)&out[base + (size_t)t * (NNODE * 4)]);
            a[t] = *(float4*)&v;
        }
    }

    // EMA (back-to-front)
#pragma unroll
    for (int t = T_IN - 1; t >= 1; --t) {
        a[t].x = 0.8f * a[t].x + 0.2f * a[t - 1].x;
        a[t].y = 0.8f * a[t].y + 0.2f * a[t - 1].y;
        a[t].z = 0.8f * a[t].z + 0.2f * a[t - 1].z;
        a[t].w = 0.8f * a[t].w + 0.2f * a[t - 1].w;
    }

#pragma unroll
    for (int jo = 0; jo < JJ; ++jo) {
        float4 s;
        s.x = sBc[jo]; s.y = sBc[jo]; s.z = sBc[jo]; s.w = sBc[jo];
#pragma unroll
        for (int t = 0; t < T_IN; ++t) {
            float wv = sWc[jo][t];
            s.x += a[t].x * wv; s.y += a[t].y * wv;
            s.z += a[t].z * wv; s.w += a[t].w * wv;
        }
        s.x = (s.x > 0.f) ? 1.0507009873554805f * s.x
                          : 1.7580993408473766f * (__expf(s.x) - 1.f);
        s.y = (s.y > 0.f) ? 1.0507009873554805f * s.y
                          : 1.7580993408473766f * (__expf(s.y) - 1.f);
        s.z = (s.z > 0.f) ? 1.0507009873554805f * s.z
                          : 1.7580993408473766f * (__expf(s.z) - 1.f);
        s.w = (s.w > 0.f) ? 1.0507009873554805f * s.w
                          : 1.7580993408473766f * (__expf(s.w) - 1.f);
        nt_store4(s, &out[base + (size_t)jo * (NNODE * 4)]);
    }
}

extern "C" void kernel_launch(void* const* d_in, const int* in_sizes, int n_in,
                              void* d_out, int out_size, void* d_ws, size_t ws_size,
                              hipStream_t stream) {
    const float* x        = (const float*)d_in[0];
    const int*   nn       = (const int*)d_in[1];
    const float* agg_w    = (const float*)d_in[2];
    const float* agg_b    = (const float*)d_in[3];
    const float* mh_w     = (const float*)d_in[4];
    const float* mh_b     = (const float*)d_in[5];
    const float* shrink_w = (const float*)d_in[6];
    const float* shrink_b = (const float*)d_in[7];
    float4* out = (float4*)d_out;
    us4* ws = (us4*)d_ws;

    const int gridA = NXCD * PAIRS_PER_XCD * CHUNKS_PER_SLICE;
    const int gridB = (BB * NNODE * 4) / 256;

    if (ws_size >= WS_BF16_BYTES) {
        gather_swish<1><<<gridA, 256, 0, stream>>>((const float4*)x, nn, agg_w, agg_b, out, ws);
        ema_shrink<1><<<gridB, 256, 0, stream>>>(mh_w, mh_b, shrink_w, shrink_b, out, ws);
    } else {
        gather_swish<0><<<gridA, 256, 0, stream>>>((const float4*)x, nn, agg_w, agg_b, out, ws);
        ema_shrink<0><<<gridB, 256, 0, stream>>>(mh_w, mh_b, shrink_w, shrink_b, out, ws);
    }
}

// Round 7
// 69.418 us; speedup vs baseline: 1.4783x; 1.0079x over previous
//
#include <hip/hip_runtime.h>

#define BB 4
#define T_IN 12
#define T_OUT 24
#define NNODE 20000
#define CC 16
#define KP1 9
#define NH 8
#define JJ 12                    // T_OUT - T_IN
#define NODES_PER_BLK 64         // 64 nodes x 4 float4-lanes = 256 threads
#define CHUNKS_PER_SLICE 313     // ceil(20000/64)
#define NXCD 8
#define NSLICE (BB * T_IN)       // 48 (b,t) slices
#define SLICES_PER_XCD (NSLICE / NXCD)      // 6
#define PAIRS_PER_XCD (SLICES_PER_XCD / 2)  // 3
#define WS_BF16_BYTES ((size_t)BB * T_IN * NNODE * CC * 2)  // 30.72 MB

typedef __attribute__((ext_vector_type(4))) float f4;
typedef __attribute__((ext_vector_type(4))) unsigned short us4;

__device__ __forceinline__ float swish1(float s) {
    return s / (1.f + __expf(-0.8f * s));
}
__device__ __forceinline__ void nt_store4(const float4& v, float4* p) {
    __builtin_nontemporal_store(*(const f4*)&v, (f4*)p);
}
__device__ __forceinline__ ushort bf16_rne(float f) {
    unsigned u = __float_as_uint(f);
    return (ushort)((u + 0x7FFFu + ((u >> 16) & 1u)) >> 16);
}
__device__ __forceinline__ us4 pack_bf16x4(const float4& v) {
    us4 r;
    r.x = bf16_rne(v.x); r.y = bf16_rne(v.y);
    r.z = bf16_rne(v.z); r.w = bf16_rne(v.w);
    return r;
}
__device__ __forceinline__ float4 unpack_bf16x4(us4 v) {
    float4 r;
    r.x = __uint_as_float((unsigned)v.x << 16);
    r.y = __uint_as_float((unsigned)v.y << 16);
    r.z = __uint_as_float((unsigned)v.z << 16);
    r.w = __uint_as_float((unsigned)v.w << 16);
    return r;
}

// Phase A: two (b,t) slices per block. XCD-pinned slices keep the 2.56 MB
// gather working set L2-resident. All 18 gather float4s are preloaded into
// register arrays (full MLP — the round-6 profile showed VGPR=32 meant only
// ~3 outstanding loads/wave, latency-serializing the gather stream).
// __launch_bounds__(256,4): allow up to 128 VGPR, keep >=16 waves/CU.
template <int BF16>
__global__ __launch_bounds__(256, 4) void gather_swish(
    const float4* __restrict__ x,    // (B,12,N,16) as float4
    const int* __restrict__ nn,      // (N,9)
    const float* __restrict__ agg_w, // (9,)
    const float* __restrict__ agg_b, // (1,)
    float4* __restrict__ out,        // (B,24,N,16) as float4
    us4* __restrict__ ws)            // (B,12,N,16) bf16 as us4
{
    __shared__ int sNN[NODES_PER_BLK * KP1];   // 576 ints

    const int xcd = blockIdx.x & (NXCD - 1);
    const int j = blockIdx.x >> 3;
    const int pair = j / CHUNKS_PER_SLICE;           // 0..2
    const int chunk = j - pair * CHUNKS_PER_SLICE;
    const int slice0 = xcd * SLICES_PER_XCD + pair * 2;  // = b*12 + t0
    const int b = slice0 / T_IN;
    const int t0 = slice0 - b * T_IN;

    const int tid = threadIdx.x;
    const int n_base = chunk * NODES_PER_BLK;

    for (int i = tid; i < NODES_PER_BLK * KP1; i += 256) {
        int gi = n_base * KP1 + i;
        sNN[i] = (gi < NNODE * KP1) ? nn[gi] : NNODE;
    }
    __syncthreads();

    const int r = tid >> 2;            // local node 0..63
    const int q = tid & 3;             // float4 lane (channels 4q..4q+3)
    const int n = n_base + r;
    if (n >= NNODE) return;

    int idx[KP1];
    float w[KP1];
#pragma unroll
    for (int k = 0; k < KP1; ++k) {
        idx[k] = sNN[r * KP1 + k];
        w[k] = agg_w[k];
        if (idx[k] >= NNODE) { idx[k] = 0; w[k] = 0.f; }  // padded zero-node
    }

    const float bias = agg_b[0];
    const float4* xs0 = x + (size_t)slice0 * (NNODE * 4) + q;
    const float4* xs1 = xs0 + (NNODE * 4);

    // ---- issue ALL loads first (MLP), then accumulate ----
    float4 v0[KP1], v1[KP1], xv0, xv1;
#pragma unroll
    for (int k = 0; k < KP1; ++k) v0[k] = xs0[(size_t)idx[k] * 4];
#pragma unroll
    for (int k = 0; k < KP1; ++k) v1[k] = xs1[(size_t)idx[k] * 4];
    xv0 = xs0[(size_t)n * 4];
    xv1 = xs1[(size_t)n * 4];

    float4 s0, s1;
    s0.x = s0.y = s0.z = s0.w = bias;
    s1.x = s1.y = s1.z = s1.w = bias;
#pragma unroll
    for (int k = 0; k < KP1; ++k) {
        float wk = w[k];
        s0.x += wk * v0[k].x; s0.y += wk * v0[k].y;
        s0.z += wk * v0[k].z; s0.w += wk * v0[k].w;
        s1.x += wk * v1[k].x; s1.y += wk * v1[k].y;
        s1.z += wk * v1[k].z; s1.w += wk * v1[k].w;
    }
    s0.x = swish1(s0.x); s0.y = swish1(s0.y); s0.z = swish1(s0.z); s0.w = swish1(s0.w);
    s1.x = swish1(s1.x); s1.y = swish1(s1.y); s1.z = swish1(s1.z); s1.w = swish1(s1.w);

    const size_t out_b = (size_t)b * (T_OUT * NNODE * 4);
    const size_t row = (size_t)n * 4 + q;
    nt_store4(xv0, &out[out_b + (size_t)t0 * (NNODE * 4) + row]);
    nt_store4(xv1, &out[out_b + (size_t)(t0 + 1) * (NNODE * 4) + row]);
    if (BF16) {
        const size_t srow = (size_t)slice0 * (NNODE * 4) + row;
        __builtin_nontemporal_store(pack_bf16x4(s0), &ws[srow]);
        __builtin_nontemporal_store(pack_bf16x4(s1), &ws[srow + (NNODE * 4)]);
    } else {
        nt_store4(s0, &out[out_b + (size_t)(T_IN + t0) * (NNODE * 4) + row]);
        nt_store4(s1, &out[out_b + (size_t)(T_IN + t0 + 1) * (NNODE * 4) + row]);
    }
}

// Phase B: EMA over t, collapsed 12x12 matmul, selu; reads staged a (bf16 ws
// or f32 in-place), writes y to out[:, 12:].
template <int BF16>
__global__ __launch_bounds__(256) void ema_shrink(
    const float* __restrict__ mh_w,      // (8,)
    const float* __restrict__ mh_b,      // (8,)
    const float* __restrict__ shrink_w,  // (12,96)
    const float* __restrict__ shrink_b,  // (12,)
    float4* __restrict__ out,            // (B,24,N,16) as float4
    const us4* __restrict__ ws)          // (B,12,N,16) bf16 as us4
{
    __shared__ float sWc[JJ][T_IN];
    __shared__ float sBc[JJ];
    const int tid = threadIdx.x;

    if (tid < JJ * T_IN) {
        int jo = tid / T_IN, t = tid - jo * T_IN;
        float s = 0.f;
#pragma unroll
        for (int h = 0; h < NH; ++h)
            s += mh_w[h] * shrink_w[jo * (T_IN * NH) + t * NH + h];
        sWc[jo][t] = s;
    }
    if (tid < JJ) {
        float s = shrink_b[tid];
#pragma unroll
        for (int qq = 0; qq < T_IN * NH; ++qq)
            s += mh_b[qq & (NH - 1)] * shrink_w[tid * (T_IN * NH) + qq];
        sBc[tid] = s;
    }
    __syncthreads();

    const int g = blockIdx.x * 256 + tid;      // (b, n*4+q) flat, coalesced
    const int b = g / (NNODE * 4);
    const int rem = g - b * (NNODE * 4);
    const size_t base = ((size_t)b * T_OUT + T_IN) * (NNODE * 4) + rem;
    const size_t sbase = (size_t)b * (T_IN * NNODE * 4) + rem;

    float4 a[T_IN];
#pragma unroll
    for (int t = 0; t < T_IN; ++t) {
        if (BF16) {
            us4 v = __builtin_nontemporal_load(&ws[sbase + (size_t)t * (NNODE * 4)]);
            a[t] = unpack_bf16x4(v);
        } else {
            f4 v = __builtin_nontemporal_load((const f4*)&out[base + (size_t)t * (NNODE * 4)]);
            a[t] = *(float4*)&v;
        }
    }

    // EMA (back-to-front)
#pragma unroll
    for (int t = T_IN - 1; t >= 1; --t) {
        a[t].x = 0.8f * a[t].x + 0.2f * a[t - 1].x;
        a[t].y = 0.8f * a[t].y + 0.2f * a[t - 1].y;
        a[t].z = 0.8f * a[t].z + 0.2f * a[t - 1].z;
        a[t].w = 0.8f * a[t].w + 0.2f * a[t - 1].w;
    }

#pragma unroll
    for (int jo = 0; jo < JJ; ++jo) {
        float4 s;
        s.x = sBc[jo]; s.y = sBc[jo]; s.z = sBc[jo]; s.w = sBc[jo];
#pragma unroll
        for (int t = 0; t < T_IN; ++t) {
            float wv = sWc[jo][t];
            s.x += a[t].x * wv; s.y += a[t].y * wv;
            s.z += a[t].z * wv; s.w += a[t].w * wv;
        }
        s.x = (s.x > 0.f) ? 1.0507009873554805f * s.x
                          : 1.7580993408473766f * (__expf(s.x) - 1.f);
        s.y = (s.y > 0.f) ? 1.0507009873554805f * s.y
                          : 1.7580993408473766f * (__expf(s.y) - 1.f);
        s.z = (s.z > 0.f) ? 1.0507009873554805f * s.z
                          : 1.7580993408473766f * (__expf(s.z) - 1.f);
        s.w = (s.w > 0.f) ? 1.0507009873554805f * s.w
                          : 1.7580993408473766f * (__expf(s.w) - 1.f);
        nt_store4(s, &out[base + (size_t)jo * (NNODE * 4)]);
    }
}

extern "C" void kernel_launch(void* const* d_in, const int* in_sizes, int n_in,
                              void* d_out, int out_size, void* d_ws, size_t ws_size,
                              hipStream_t stream) {
    const float* x        = (const float*)d_in[0];
    const int*   nn       = (const int*)d_in[1];
    const float* agg_w    = (const float*)d_in[2];
    const float* agg_b    = (const float*)d_in[3];
    const float* mh_w     = (const float*)d_in[4];
    const float* mh_b     = (const float*)d_in[5];
    const float* shrink_w = (const float*)d_in[6];
    const float* shrink_b = (const float*)d_in[7];
    float4* out = (float4*)d_out;
    us4* ws = (us4*)d_ws;

    const int gridA = NXCD * PAIRS_PER_XCD * CHUNKS_PER_SLICE;
    const int gridB = (BB * NNODE * 4) / 256;

    if (ws_size >= WS_BF16_BYTES) {
        gather_swish<1><<<gridA, 256, 0, stream>>>((const float4*)x, nn, agg_w, agg_b, out, ws);
        ema_shrink<1><<<gridB, 256, 0, stream>>>(mh_w, mh_b, shrink_w, shrink_b, out, ws);
    } else {
        gather_swish<0><<<gridA, 256, 0, stream>>>((const float4*)x, nn, agg_w, agg_b, out, ws);
        ema_shrink<0><<<gridB, 256, 0, stream>>>(mh_w, mh_b, shrink_w, shrink_b, out, ws);
    }
}

// Round 8
// 69.117 us; speedup vs baseline: 1.4848x; 1.0044x over previous
//
#include <hip/hip_runtime.h>

#define BB 4
#define T_IN 12
#define T_OUT 24
#define NNODE 20000
#define CC 16
#define KP1 9
#define NH 8
#define JJ 12                    // T_OUT - T_IN
#define NODES_PER_BLK 64         // 64 nodes x 4 float4-lanes = 256 threads
#define CHUNKS_PER_SLICE 313     // ceil(20000/64)
#define NXCD 8
#define NSLICE (BB * T_IN)       // 48 (b,t) slices
#define SLICES_PER_XCD (NSLICE / NXCD)      // 6
#define PAIRS_PER_XCD (SLICES_PER_XCD / 2)  // 3
#define WS_BF16_BYTES ((size_t)BB * T_IN * NNODE * CC * 2)  // 30.72 MB

typedef __attribute__((ext_vector_type(4))) float f4;
typedef __attribute__((ext_vector_type(4))) unsigned short us4;

__device__ __forceinline__ float swish1(float s) {
    return s / (1.f + __expf(-0.8f * s));
}
__device__ __forceinline__ void nt_store4(const float4& v, float4* p) {
    __builtin_nontemporal_store(*(const f4*)&v, (f4*)p);
}
__device__ __forceinline__ ushort bf16_rne(float f) {
    unsigned u = __float_as_uint(f);
    return (ushort)((u + 0x7FFFu + ((u >> 16) & 1u)) >> 16);
}
__device__ __forceinline__ us4 pack_bf16x4(const float4& v) {
    us4 r;
    r.x = bf16_rne(v.x); r.y = bf16_rne(v.y);
    r.z = bf16_rne(v.z); r.w = bf16_rne(v.w);
    return r;
}
__device__ __forceinline__ float4 unpack_bf16x4(us4 v) {
    float4 r;
    r.x = __uint_as_float((unsigned)v.x << 16);
    r.y = __uint_as_float((unsigned)v.y << 16);
    r.z = __uint_as_float((unsigned)v.z << 16);
    r.w = __uint_as_float((unsigned)v.w << 16);
    return r;
}

// Phase A: two (b,t) slices per block. XCD-pinned slices keep the 2.56 MB
// gather working set L2-resident. All 20 loads are issued BEFORE a
// sched_barrier(0); the compiler must keep every result live (VGPR ~100+),
// giving 18-deep per-wave memory parallelism. This is the decisive test
// between "per-wave latency window" and "per-CU MSHR cap" models.
template <int BF16>
__global__ __launch_bounds__(256, 4) void gather_swish(
    const float4* __restrict__ x,    // (B,12,N,16) as float4
    const int* __restrict__ nn,      // (N,9)
    const float* __restrict__ agg_w, // (9,)
    const float* __restrict__ agg_b, // (1,)
    float4* __restrict__ out,        // (B,24,N,16) as float4
    us4* __restrict__ ws)            // (B,12,N,16) bf16 as us4
{
    __shared__ int sNN[NODES_PER_BLK * KP1];   // 576 ints

    const int xcd = blockIdx.x & (NXCD - 1);
    const int j = blockIdx.x >> 3;
    const int pair = j / CHUNKS_PER_SLICE;           // 0..2
    const int chunk = j - pair * CHUNKS_PER_SLICE;
    const int slice0 = xcd * SLICES_PER_XCD + pair * 2;  // = b*12 + t0
    const int b = slice0 / T_IN;
    const int t0 = slice0 - b * T_IN;

    const int tid = threadIdx.x;
    const int n_base = chunk * NODES_PER_BLK;

    for (int i = tid; i < NODES_PER_BLK * KP1; i += 256) {
        int gi = n_base * KP1 + i;
        sNN[i] = (gi < NNODE * KP1) ? nn[gi] : NNODE;
    }
    __syncthreads();

    const int r = tid >> 2;            // local node 0..63
    const int q = tid & 3;             // float4 lane (channels 4q..4q+3)
    const int n = n_base + r;
    if (n >= NNODE) return;

    int idx[KP1];
    float w[KP1];
#pragma unroll
    for (int k = 0; k < KP1; ++k) {
        idx[k] = sNN[r * KP1 + k];
        w[k] = agg_w[k];
        if (idx[k] >= NNODE) { idx[k] = 0; w[k] = 0.f; }  // padded zero-node
    }

    const float bias = agg_b[0];
    const float4* xs0 = x + (size_t)slice0 * (NNODE * 4) + q;
    const float4* xs1 = xs0 + (NNODE * 4);

    // ---- issue ALL 20 loads, then hard-fence the scheduler ----
    float4 v0[KP1], v1[KP1], xv0, xv1;
#pragma unroll
    for (int k = 0; k < KP1; ++k) {
        v0[k] = xs0[(size_t)idx[k] * 4];
        v1[k] = xs1[(size_t)idx[k] * 4];
    }
    xv0 = xs0[(size_t)n * 4];
    xv1 = xs1[(size_t)n * 4];
    __builtin_amdgcn_sched_barrier(0);   // nothing moves across: all loads in flight

    float4 s0, s1;
    s0.x = s0.y = s0.z = s0.w = bias;
    s1.x = s1.y = s1.z = s1.w = bias;
#pragma unroll
    for (int k = 0; k < KP1; ++k) {
        float wk = w[k];
        s0.x += wk * v0[k].x; s0.y += wk * v0[k].y;
        s0.z += wk * v0[k].z; s0.w += wk * v0[k].w;
        s1.x += wk * v1[k].x; s1.y += wk * v1[k].y;
        s1.z += wk * v1[k].z; s1.w += wk * v1[k].w;
    }
    s0.x = swish1(s0.x); s0.y = swish1(s0.y); s0.z = swish1(s0.z); s0.w = swish1(s0.w);
    s1.x = swish1(s1.x); s1.y = swish1(s1.y); s1.z = swish1(s1.z); s1.w = swish1(s1.w);

    const size_t out_b = (size_t)b * (T_OUT * NNODE * 4);
    const size_t row = (size_t)n * 4 + q;
    nt_store4(xv0, &out[out_b + (size_t)t0 * (NNODE * 4) + row]);
    nt_store4(xv1, &out[out_b + (size_t)(t0 + 1) * (NNODE * 4) + row]);
    if (BF16) {
        const size_t srow = (size_t)slice0 * (NNODE * 4) + row;
        __builtin_nontemporal_store(pack_bf16x4(s0), &ws[srow]);
        __builtin_nontemporal_store(pack_bf16x4(s1), &ws[srow + (NNODE * 4)]);
    } else {
        nt_store4(s0, &out[out_b + (size_t)(T_IN + t0) * (NNODE * 4) + row]);
        nt_store4(s1, &out[out_b + (size_t)(T_IN + t0 + 1) * (NNODE * 4) + row]);
    }
}

// Phase B: EMA over t, collapsed 12x12 matmul, selu; reads staged a (bf16 ws
// or f32 in-place), writes y to out[:, 12:].
template <int BF16>
__global__ __launch_bounds__(256) void ema_shrink(
    const float* __restrict__ mh_w,      // (8,)
    const float* __restrict__ mh_b,      // (8,)
    const float* __restrict__ shrink_w,  // (12,96)
    const float* __restrict__ shrink_b,  // (12,)
    float4* __restrict__ out,            // (B,24,N,16) as float4
    const us4* __restrict__ ws)          // (B,12,N,16) bf16 as us4
{
    __shared__ float sWc[JJ][T_IN];
    __shared__ float sBc[JJ];
    const int tid = threadIdx.x;

    if (tid < JJ * T_IN) {
        int jo = tid / T_IN, t = tid - jo * T_IN;
        float s = 0.f;
#pragma unroll
        for (int h = 0; h < NH; ++h)
            s += mh_w[h] * shrink_w[jo * (T_IN * NH) + t * NH + h];
        sWc[jo][t] = s;
    }
    if (tid < JJ) {
        float s = shrink_b[tid];
#pragma unroll
        for (int qq = 0; qq < T_IN * NH; ++qq)
            s += mh_b[qq & (NH - 1)] * shrink_w[tid * (T_IN * NH) + qq];
        sBc[tid] = s;
    }
    __syncthreads();

    const int g = blockIdx.x * 256 + tid;      // (b, n*4+q) flat, coalesced
    const int b = g / (NNODE * 4);
    const int rem = g - b * (NNODE * 4);
    const size_t base = ((size_t)b * T_OUT + T_IN) * (NNODE * 4) + rem;
    const size_t sbase = (size_t)b * (T_IN * NNODE * 4) + rem;

    float4 a[T_IN];
#pragma unroll
    for (int t = 0; t < T_IN; ++t) {
        if (BF16) {
            us4 v = __builtin_nontemporal_load(&ws[sbase + (size_t)t * (NNODE * 4)]);
            a[t] = unpack_bf16x4(v);
        } else {
            f4 v = __builtin_nontemporal_load((const f4*)&out[base + (size_t)t * (NNODE * 4)]);
            a[t] = *(float4*)&v;
        }
    }

    // EMA (back-to-front)
#pragma unroll
    for (int t = T_IN - 1; t >= 1; --t) {
        a[t].x = 0.8f * a[t].x + 0.2f * a[t - 1].x;
        a[t].y = 0.8f * a[t].y + 0.2f * a[t - 1].y;
        a[t].z = 0.8f * a[t].z + 0.2f * a[t - 1].z;
        a[t].w = 0.8f * a[t].w + 0.2f * a[t - 1].w;
    }

#pragma unroll
    for (int jo = 0; jo < JJ; ++jo) {
        float4 s;
        s.x = sBc[jo]; s.y = sBc[jo]; s.z = sBc[jo]; s.w = sBc[jo];
#pragma unroll
        for (int t = 0; t < T_IN; ++t) {
            float wv = sWc[jo][t];
            s.x += a[t].x * wv; s.y += a[t].y * wv;
            s.z += a[t].z * wv; s.w += a[t].w * wv;
        }
        s.x = (s.x > 0.f) ? 1.0507009873554805f * s.x
                          : 1.7580993408473766f * (__expf(s.x) - 1.f);
        s.y = (s.y > 0.f) ? 1.0507009873554805f * s.y
                          : 1.7580993408473766f * (__expf(s.y) - 1.f);
        s.z = (s.z > 0.f) ? 1.0507009873554805f * s.z
                          : 1.7580993408473766f * (__expf(s.z) - 1.f);
        s.w = (s.w > 0.f) ? 1.0507009873554805f * s.w
                          : 1.7580993408473766f * (__expf(s.w) - 1.f);
        nt_store4(s, &out[base + (size_t)jo * (NNODE * 4)]);
    }
}

extern "C" void kernel_launch(void* const* d_in, const int* in_sizes, int n_in,
                              void* d_out, int out_size, void* d_ws, size_t ws_size,
                              hipStream_t stream) {
    const float* x        = (const float*)d_in[0];
    const int*   nn       = (const int*)d_in[1];
    const float* agg_w    = (const float*)d_in[2];
    const float* agg_b    = (const float*)d_in[3];
    const float* mh_w     = (const float*)d_in[4];
    const float* mh_b     = (const float*)d_in[5];
    const float* shrink_w = (const float*)d_in[6];
    const float* shrink_b = (const float*)d_in[7];
    float4* out = (float4*)d_out;
    us4* ws = (us4*)d_ws;

    const int gridA = NXCD * PAIRS_PER_XCD * CHUNKS_PER_SLICE;
    const int gridB = (BB * NNODE * 4) / 256;

    if (ws_size >= WS_BF16_BYTES) {
        gather_swish<1><<<gridA, 256, 0, stream>>>((const float4*)x, nn, agg_w, agg_b, out, ws);
        ema_shrink<1><<<gridB, 256, 0, stream>>>(mh_w, mh_b, shrink_w, shrink_b, out, ws);
    } else {
        gather_swish<0><<<gridA, 256, 0, stream>>>((const float4*)x, nn, agg_w, agg_b, out, ws);
        ema_shrink<0><<<gridB, 256, 0, stream>>>(mh_w, mh_b, shrink_w, shrink_b, out, ws);
    }
}